// Round 1
// baseline (1948.650 us; speedup 1.0000x reference)
//
#include <hip/hip_runtime.h>
#include <math.h>

#define NNODES 50000
#define E0 800000
#define ETOT 850000
#define IN_DIM 1024
#define HID 64
#define HEADS 4
#define C1 256      // HEADS*HID
#define C2 128      // OUT_DIM
#define NEG_SLOPE 0.2f

// ---------- helpers ----------
__device__ __forceinline__ unsigned f2ord(float f) {
    unsigned u = __float_as_uint(f);
    return (u & 0x80000000u) ? ~u : (u | 0x80000000u);
}
__device__ __forceinline__ float ord2f(unsigned d) {
    unsigned u = (d & 0x80000000u) ? (d & 0x7fffffffu) : ~d;
    return __uint_as_float(u);
}
__device__ __forceinline__ void edge_sd(const int* __restrict__ ei, int e, int& s, int& d) {
    if (e < E0) { s = ei[e]; d = ei[E0 + e]; }
    else        { s = e - E0; d = s; }
}

// ---------- GEMM: C[M,N] = A[M,K] @ B[K,N], row-major, f32 ----------
#define BM 64
#define BN 64
#define BK 16
__global__ __launch_bounds__(256) void sgemm_kernel(const float* __restrict__ A,
                                                    const float* __restrict__ B,
                                                    float* __restrict__ C,
                                                    int M, int N, int K)
{
    __shared__ float As[BK][BM];
    __shared__ float Bs[BK][BN];
    const int tid = threadIdx.x;
    const int tx = tid & 15;          // 0..15 (col group)
    const int ty = tid >> 4;          // 0..15 (row group)
    const int rowBase = blockIdx.x * BM;
    const int colBase = blockIdx.y * BN;

    const int arow = tid >> 2;        // 0..63
    const int ak   = (tid & 3) << 2;  // 0,4,8,12
    const int brow = tid >> 4;        // 0..15
    const int bcol = (tid & 15) << 2; // 0..60

    const int aRowIdx = rowBase + arow;
    const bool aValid = aRowIdx < M;
    const float* Aptr = A + (size_t)aRowIdx * K;

    float acc[4][4] = {};

    for (int kt = 0; kt < K; kt += BK) {
        float4 av = make_float4(0.f, 0.f, 0.f, 0.f);
        if (aValid) av = *(const float4*)(Aptr + kt + ak);
        float4 bv = *(const float4*)(B + (size_t)(kt + brow) * N + colBase + bcol);
        As[ak + 0][arow] = av.x;
        As[ak + 1][arow] = av.y;
        As[ak + 2][arow] = av.z;
        As[ak + 3][arow] = av.w;
        *(float4*)&Bs[brow][bcol] = bv;
        __syncthreads();
        #pragma unroll
        for (int k = 0; k < BK; ++k) {
            float a[4], b[4];
            *(float4*)a = *(const float4*)&As[k][ty << 2];
            *(float4*)b = *(const float4*)&Bs[k][tx << 2];
            #pragma unroll
            for (int i = 0; i < 4; ++i)
                #pragma unroll
                for (int j = 0; j < 4; ++j)
                    acc[i][j] = fmaf(a[i], b[j], acc[i][j]);
        }
        __syncthreads();
    }

    #pragma unroll
    for (int i = 0; i < 4; ++i) {
        int row = rowBase + (ty << 2) + i;
        if (row < M) {
            float4 o = make_float4(acc[i][0], acc[i][1], acc[i][2], acc[i][3]);
            *(float4*)(C + (size_t)row * N + colBase + (tx << 2)) = o;
        }
    }
}

// ---------- per-node attention halves, layer 1 (H=4, D=64, 256 threads) ----------
__global__ __launch_bounds__(256) void alpha1_kernel(const float* __restrict__ h1,
                                                     const float* __restrict__ asrc,
                                                     const float* __restrict__ adst,
                                                     float* __restrict__ out_s,
                                                     float* __restrict__ out_d)
{
    int n = blockIdx.x;
    int t = threadIdx.x;
    float h = h1[(size_t)n * C1 + t];
    float s = h * asrc[t];
    float d = h * adst[t];
    #pragma unroll
    for (int off = 32; off > 0; off >>= 1) {
        s += __shfl_down(s, off);
        d += __shfl_down(d, off);
    }
    if ((t & 63) == 0) {
        out_s[n * HEADS + (t >> 6)] = s;
        out_d[n * HEADS + (t >> 6)] = d;
    }
}

// ---------- per-node attention halves, layer 2 (H=1, D=128, 64 threads) ----------
__global__ __launch_bounds__(64) void alpha2_kernel(const float* __restrict__ h2,
                                                    const float* __restrict__ asrc,
                                                    const float* __restrict__ adst,
                                                    float* __restrict__ out_s,
                                                    float* __restrict__ out_d)
{
    int n = blockIdx.x;
    int t = threadIdx.x;
    float a = h2[(size_t)n * C2 + t];
    float b = h2[(size_t)n * C2 + t + 64];
    float s = a * asrc[t] + b * asrc[t + 64];
    float d = a * adst[t] + b * adst[t + 64];
    #pragma unroll
    for (int off = 32; off > 0; off >>= 1) {
        s += __shfl_down(s, off);
        d += __shfl_down(d, off);
    }
    if (t == 0) { out_s[n] = s; out_d[n] = d; }
}

// ---------- edge pass 1: e = lrelu(as[s]+ad[d]); store; segment max ----------
template <int H>
__global__ __launch_bounds__(256) void edge_max_kernel(const int* __restrict__ ei,
                                                       const float* __restrict__ as,
                                                       const float* __restrict__ ad,
                                                       float* __restrict__ ebuf,
                                                       unsigned* __restrict__ mbits)
{
    int e = blockIdx.x * blockDim.x + threadIdx.x;
    if (e >= ETOT) return;
    int s, d; edge_sd(ei, e, s, d);
    #pragma unroll
    for (int h = 0; h < H; ++h) {
        float v = as[s * H + h] + ad[d * H + h];
        v = v > 0.f ? v : NEG_SLOPE * v;
        ebuf[(size_t)e * H + h] = v;
        atomicMax(&mbits[d * H + h], f2ord(v));
    }
}

// ---------- edge pass 2: w = exp(e - m[d]); store; segment sum ----------
template <int H>
__global__ __launch_bounds__(256) void edge_exp_kernel(const int* __restrict__ ei,
                                                       const unsigned* __restrict__ mbits,
                                                       float* __restrict__ ebuf,
                                                       float* __restrict__ ssum)
{
    int e = blockIdx.x * blockDim.x + threadIdx.x;
    if (e >= ETOT) return;
    int s, d; edge_sd(ei, e, s, d);
    #pragma unroll
    for (int h = 0; h < H; ++h) {
        float m = ord2f(mbits[d * H + h]);
        float w = expf(ebuf[(size_t)e * H + h] - m);
        ebuf[(size_t)e * H + h] = w;
        atomicAdd(&ssum[d * H + h], w);
    }
}

// ---------- edge pass 3 layer1: out[d] += alpha * h1[s], 256 ch ----------
__global__ __launch_bounds__(256) void edge_aggr1_kernel(const int* __restrict__ ei,
                                                         const float* __restrict__ h1,
                                                         const float* __restrict__ ebuf,
                                                         const float* __restrict__ ssum,
                                                         float* __restrict__ out1)
{
    int e = blockIdx.x;
    int t = threadIdx.x;
    int h = t >> 6;
    int s, d; edge_sd(ei, e, s, d);
    float alpha = ebuf[(size_t)e * HEADS + h] / (ssum[d * HEADS + h] + 1e-16f);
    atomicAdd(&out1[(size_t)d * C1 + t], h1[(size_t)s * C1 + t] * alpha);
}

// ---------- edge pass 3 layer2: out[d] += alpha * h2[s], 128 ch ----------
__global__ __launch_bounds__(128) void edge_aggr2_kernel(const int* __restrict__ ei,
                                                         const float* __restrict__ h2,
                                                         const float* __restrict__ ebuf,
                                                         const float* __restrict__ ssum,
                                                         float* __restrict__ out2)
{
    int e = blockIdx.x;
    int t = threadIdx.x;
    int s, d; edge_sd(ei, e, s, d);
    float alpha = ebuf[e] / (ssum[d] + 1e-16f);
    atomicAdd(&out2[(size_t)d * C2 + t], h2[(size_t)s * C2 + t] * alpha);
}

// ---------- bias + ELU, in place, n = NNODES*C1 ----------
__global__ __launch_bounds__(256) void elu_kernel(float* __restrict__ x,
                                                  const float* __restrict__ b)
{
    size_t n = (size_t)NNODES * C1;
    for (size_t i = (size_t)blockIdx.x * blockDim.x + threadIdx.x; i < n;
         i += (size_t)gridDim.x * blockDim.x) {
        float v = x[i] + b[i & (C1 - 1)];
        x[i] = v > 0.f ? v : (expf(v) - 1.f);
    }
}

// ---------- bias + L2 normalize, in place on d_out ----------
__global__ __launch_bounds__(64) void norm_kernel(float* __restrict__ out,
                                                  const float* __restrict__ b2)
{
    int n = blockIdx.x;
    int t = threadIdx.x;
    float a = out[(size_t)n * C2 + t] + b2[t];
    float b = out[(size_t)n * C2 + t + 64] + b2[t + 64];
    float sq = a * a + b * b;
    #pragma unroll
    for (int off = 32; off > 0; off >>= 1) sq += __shfl_down(sq, off);
    sq = __shfl(sq, 0);
    float inv = 1.0f / fmaxf(sqrtf(sq), 1e-12f);
    out[(size_t)n * C2 + t] = a * inv;
    out[(size_t)n * C2 + t + 64] = b * inv;
}

extern "C" void kernel_launch(void* const* d_in, const int* in_sizes, int n_in,
                              void* d_out, int out_size, void* d_ws, size_t ws_size,
                              hipStream_t stream)
{
    const float* x     = (const float*)d_in[0];
    const int*   ei    = (const int*)d_in[1];
    const float* W1    = (const float*)d_in[2];
    const float* asrc1 = (const float*)d_in[3];
    const float* adst1 = (const float*)d_in[4];
    const float* b1    = (const float*)d_in[5];
    const float* W2    = (const float*)d_in[6];
    const float* asrc2 = (const float*)d_in[7];
    const float* adst2 = (const float*)d_in[8];
    const float* b2    = (const float*)d_in[9];
    float* out = (float*)d_out;

    char* ws = (char*)d_ws;
    size_t off = 0;
    auto alloc = [&](size_t nfloats) {
        float* p = (float*)(ws + off);
        off += nfloats * sizeof(float);
        return p;
    };
    float*    h1   = alloc((size_t)NNODES * C1);   // 51.2 MB
    float*    act1 = alloc((size_t)NNODES * C1);   // 51.2 MB (aggr out, then ELU in place)
    float*    ebuf = alloc((size_t)ETOT * HEADS);  // 13.6 MB
    float*    as1  = alloc((size_t)NNODES * HEADS);
    float*    ad1  = alloc((size_t)NNODES * HEADS);
    unsigned* m1   = (unsigned*)alloc((size_t)NNODES * HEADS);
    float*    s1   = alloc((size_t)NNODES * HEADS);
    float*    as2  = alloc(NNODES);
    float*    ad2  = alloc(NNODES);
    unsigned* m2   = (unsigned*)alloc(NNODES);
    float*    s2   = alloc(NNODES);
    float*    h2   = h1;  // reuse: h1 dead after layer-1 aggregation

    const int eb = (ETOT + 255) / 256;

    // ---- Layer 1 ----
    dim3 g1((NNODES + BM - 1) / BM, C1 / BN);
    sgemm_kernel<<<g1, 256, 0, stream>>>(x, W1, h1, NNODES, C1, IN_DIM);
    alpha1_kernel<<<NNODES, 256, 0, stream>>>(h1, asrc1, adst1, as1, ad1);
    hipMemsetAsync(m1, 0, (size_t)NNODES * HEADS * 4, stream);
    hipMemsetAsync(s1, 0, (size_t)NNODES * HEADS * 4, stream);
    hipMemsetAsync(act1, 0, (size_t)NNODES * C1 * 4, stream);
    edge_max_kernel<HEADS><<<eb, 256, 0, stream>>>(ei, as1, ad1, ebuf, m1);
    edge_exp_kernel<HEADS><<<eb, 256, 0, stream>>>(ei, m1, ebuf, s1);
    edge_aggr1_kernel<<<ETOT, 256, 0, stream>>>(ei, h1, ebuf, s1, act1);
    elu_kernel<<<2048, 256, 0, stream>>>(act1, b1);

    // ---- Layer 2 ----
    dim3 g2((NNODES + BM - 1) / BM, C2 / BN);
    sgemm_kernel<<<g2, 256, 0, stream>>>(act1, W2, h2, NNODES, C2, C1);
    alpha2_kernel<<<NNODES, 64, 0, stream>>>(h2, asrc2, adst2, as2, ad2);
    hipMemsetAsync(m2, 0, (size_t)NNODES * 4, stream);
    hipMemsetAsync(s2, 0, (size_t)NNODES * 4, stream);
    hipMemsetAsync(out, 0, (size_t)NNODES * C2 * 4, stream);
    edge_max_kernel<1><<<eb, 256, 0, stream>>>(ei, as2, ad2, ebuf, m2);
    edge_exp_kernel<1><<<eb, 256, 0, stream>>>(ei, m2, ebuf, s2);
    edge_aggr2_kernel<<<ETOT, 128, 0, stream>>>(ei, h2, ebuf, s2, out);
    norm_kernel<<<NNODES, 64, 0, stream>>>(out, b2);
}

// Round 3
// 1010.176 us; speedup vs baseline: 1.9290x; 1.9290x over previous
//
#include <hip/hip_runtime.h>
#include <math.h>

#define NNODES 50000
#define E0 800000
#define ETOT 850000
#define IN_DIM 1024
#define HID 64
#define HEADS 4
#define C1 256      // HEADS*HID
#define C2 128      // OUT_DIM
#define NEG_SLOPE 0.2f

// ---------- helpers ----------
// NOTE: harness delivers integer inputs as int32 (verified round 1: int* passed,
// long long* faulted). Do NOT read edge_index as int64.
__device__ __forceinline__ void edge_sd(const int* __restrict__ ei, int e, int& s, int& d) {
    if (e < E0) { s = ei[e]; d = ei[E0 + e]; }
    else        { s = e - E0; d = s; }
}

// ---------- GEMM: C[M,N] = A[M,K] @ B[K,N], row-major, f32 ----------
#define BM 64
#define BN 64
#define BK 16
__global__ __launch_bounds__(256) void sgemm_kernel(const float* __restrict__ A,
                                                    const float* __restrict__ B,
                                                    float* __restrict__ C,
                                                    int M, int N, int K)
{
    __shared__ float As[BK][BM];
    __shared__ float Bs[BK][BN];
    const int tid = threadIdx.x;
    const int tx = tid & 15;
    const int ty = tid >> 4;
    const int rowBase = blockIdx.x * BM;
    const int colBase = blockIdx.y * BN;

    const int arow = tid >> 2;
    const int ak   = (tid & 3) << 2;
    const int brow = tid >> 4;
    const int bcol = (tid & 15) << 2;

    const int aRowIdx = rowBase + arow;
    const bool aValid = aRowIdx < M;
    const float* Aptr = A + (size_t)aRowIdx * K;

    float acc[4][4] = {};

    for (int kt = 0; kt < K; kt += BK) {
        float4 av = make_float4(0.f, 0.f, 0.f, 0.f);
        if (aValid) av = *(const float4*)(Aptr + kt + ak);
        float4 bv = *(const float4*)(B + (size_t)(kt + brow) * N + colBase + bcol);
        As[ak + 0][arow] = av.x;
        As[ak + 1][arow] = av.y;
        As[ak + 2][arow] = av.z;
        As[ak + 3][arow] = av.w;
        *(float4*)&Bs[brow][bcol] = bv;
        __syncthreads();
        #pragma unroll
        for (int k = 0; k < BK; ++k) {
            float a[4], b[4];
            *(float4*)a = *(const float4*)&As[k][ty << 2];
            *(float4*)b = *(const float4*)&Bs[k][tx << 2];
            #pragma unroll
            for (int i = 0; i < 4; ++i)
                #pragma unroll
                for (int j = 0; j < 4; ++j)
                    acc[i][j] = fmaf(a[i], b[j], acc[i][j]);
        }
        __syncthreads();
    }

    #pragma unroll
    for (int i = 0; i < 4; ++i) {
        int row = rowBase + (ty << 2) + i;
        if (row < M) {
            float4 o = make_float4(acc[i][0], acc[i][1], acc[i][2], acc[i][3]);
            *(float4*)(C + (size_t)row * N + colBase + (tx << 2)) = o;
        }
    }
}

// ---------- per-node attention halves, layer 1 (H=4, D=64, 256 threads) ----------
__global__ __launch_bounds__(256) void alpha1_kernel(const float* __restrict__ h1,
                                                     const float* __restrict__ asrc,
                                                     const float* __restrict__ adst,
                                                     float* __restrict__ out_s,
                                                     float* __restrict__ out_d)
{
    int n = blockIdx.x;
    int t = threadIdx.x;
    float h = h1[(size_t)n * C1 + t];
    float s = h * asrc[t];
    float d = h * adst[t];
    #pragma unroll
    for (int off = 32; off > 0; off >>= 1) {
        s += __shfl_down(s, off);
        d += __shfl_down(d, off);
    }
    if ((t & 63) == 0) {
        out_s[n * HEADS + (t >> 6)] = s;
        out_d[n * HEADS + (t >> 6)] = d;
    }
}

// ---------- per-node attention halves, layer 2 (H=1, D=128, 64 threads) ----------
__global__ __launch_bounds__(64) void alpha2_kernel(const float* __restrict__ h2,
                                                    const float* __restrict__ asrc,
                                                    const float* __restrict__ adst,
                                                    float* __restrict__ out_s,
                                                    float* __restrict__ out_d)
{
    int n = blockIdx.x;
    int t = threadIdx.x;
    float a = h2[(size_t)n * C2 + t];
    float b = h2[(size_t)n * C2 + t + 64];
    float s = a * asrc[t] + b * asrc[t + 64];
    float d = a * adst[t] + b * adst[t + 64];
    #pragma unroll
    for (int off = 32; off > 0; off >>= 1) {
        s += __shfl_down(s, off);
        d += __shfl_down(d, off);
    }
    if (t == 0) { out_s[n] = s; out_d[n] = d; }
}

// ---------- CSR build ----------
__global__ __launch_bounds__(256) void deg_kernel(const int* __restrict__ ei,
                                                  int* __restrict__ deg)
{
    int e = blockIdx.x * blockDim.x + threadIdx.x;
    if (e >= ETOT) return;
    int s, d; edge_sd(ei, e, s, d);
    atomicAdd(&deg[d], 1);
}

#define SCAN_T 1024
__global__ __launch_bounds__(SCAN_T) void scan_kernel(const int* __restrict__ deg,
                                                      int* __restrict__ rowptr)
{
    __shared__ int buf[SCAN_T];
    __shared__ int carry_s;
    int t = threadIdx.x;
    if (t == 0) carry_s = 0;
    __syncthreads();
    for (int base = 0; base < NNODES; base += SCAN_T) {
        int idx = base + t;
        int v = (idx < NNODES) ? deg[idx] : 0;
        buf[t] = v;
        __syncthreads();
        #pragma unroll
        for (int off = 1; off < SCAN_T; off <<= 1) {
            int add = (t >= off) ? buf[t - off] : 0;
            __syncthreads();
            buf[t] += add;
            __syncthreads();
        }
        int incl = buf[t];
        int carry = carry_s;
        if (idx < NNODES) rowptr[idx] = carry + incl - v;
        __syncthreads();
        if (t == SCAN_T - 1) carry_s = carry + incl;
        __syncthreads();
    }
    if (t == 0) rowptr[NNODES] = carry_s;
}

__global__ __launch_bounds__(256) void scatter_kernel(const int* __restrict__ ei,
                                                      int* __restrict__ cursor,
                                                      int* __restrict__ srcs)
{
    int e = blockIdx.x * blockDim.x + threadIdx.x;
    if (e >= ETOT) return;
    int s, d; edge_sd(ei, e, s, d);
    int pos = atomicAdd(&cursor[d], 1);
    srcs[pos] = s;
}

// ---------- layer-1 fused softmax-aggregate (+bias+ELU), one block per dst ----------
__global__ __launch_bounds__(256) void aggr1_csr(const int* __restrict__ rowptr,
                                                 const int* __restrict__ srcs,
                                                 const float* __restrict__ h1,
                                                 const float* __restrict__ as1,
                                                 const float* __restrict__ ad1,
                                                 const float* __restrict__ b1,
                                                 float* __restrict__ out)
{
    int d = blockIdx.x;
    int t = threadIdx.x;
    int head = t >> 6;
    int beg = rowptr[d], end = rowptr[d + 1];
    float add = ad1[d * HEADS + head];
    float m = -INFINITY, ssum = 0.f, acc = 0.f;
    for (int i = beg; i < end; ++i) {
        int s = srcs[i];
        float e = as1[s * HEADS + head] + add;
        e = e > 0.f ? e : NEG_SLOPE * e;
        float h = h1[(size_t)s * C1 + t];
        if (e > m) {
            float r = expf(m - e);   // exp(-inf)=0 first time
            ssum *= r; acc *= r; m = e;
        }
        float w = expf(e - m);
        ssum += w;
        acc += w * h;
    }
    float o = acc / (ssum + 1e-16f) + b1[t];
    out[(size_t)d * C1 + t] = o > 0.f ? o : (expf(o) - 1.f);
}

// ---------- layer-2 fused softmax-aggregate (+bias+L2 normalize) ----------
__global__ __launch_bounds__(128) void aggr2_csr(const int* __restrict__ rowptr,
                                                 const int* __restrict__ srcs,
                                                 const float* __restrict__ h2,
                                                 const float* __restrict__ as2,
                                                 const float* __restrict__ ad2,
                                                 const float* __restrict__ b2,
                                                 float* __restrict__ out)
{
    int d = blockIdx.x;
    int t = threadIdx.x;
    int beg = rowptr[d], end = rowptr[d + 1];
    float add = ad2[d];
    float m = -INFINITY, ssum = 0.f, acc = 0.f;
    for (int i = beg; i < end; ++i) {
        int s = srcs[i];
        float e = as2[s] + add;
        e = e > 0.f ? e : NEG_SLOPE * e;
        float h = h2[(size_t)s * C2 + t];
        if (e > m) {
            float r = expf(m - e);
            ssum *= r; acc *= r; m = e;
        }
        float w = expf(e - m);
        ssum += w;
        acc += w * h;
    }
    float o = acc / (ssum + 1e-16f) + b2[t];
    // block L2-norm reduce (2 waves)
    __shared__ float red[2];
    float sq = o * o;
    #pragma unroll
    for (int off = 32; off > 0; off >>= 1) sq += __shfl_down(sq, off);
    if ((t & 63) == 0) red[t >> 6] = sq;
    __syncthreads();
    float total = red[0] + red[1];
    float inv = 1.0f / fmaxf(sqrtf(total), 1e-12f);
    out[(size_t)d * C2 + t] = o * inv;
}

extern "C" void kernel_launch(void* const* d_in, const int* in_sizes, int n_in,
                              void* d_out, int out_size, void* d_ws, size_t ws_size,
                              hipStream_t stream)
{
    const float* x     = (const float*)d_in[0];
    const int*   ei    = (const int*)d_in[1];
    const float* W1    = (const float*)d_in[2];
    const float* asrc1 = (const float*)d_in[3];
    const float* adst1 = (const float*)d_in[4];
    const float* b1    = (const float*)d_in[5];
    const float* W2    = (const float*)d_in[6];
    const float* asrc2 = (const float*)d_in[7];
    const float* adst2 = (const float*)d_in[8];
    const float* b2    = (const float*)d_in[9];
    float* out = (float*)d_out;

    char* ws = (char*)d_ws;
    size_t off = 0;
    auto alloc = [&](size_t nfloats) {
        float* p = (float*)(ws + off);
        off += nfloats * sizeof(float);
        return p;
    };
    float* h1     = alloc((size_t)NNODES * C1);   // 51.2 MB
    float* act1   = alloc((size_t)NNODES * C1);   // 51.2 MB
    float* as1    = alloc((size_t)NNODES * HEADS);
    float* ad1    = alloc((size_t)NNODES * HEADS);
    float* as2    = alloc(NNODES);
    float* ad2    = alloc(NNODES);
    int*   deg    = (int*)alloc(NNODES);
    int*   rowptr = (int*)alloc(NNODES + 1);
    int*   cursor = (int*)alloc(NNODES + 1);
    int*   srcs   = (int*)alloc(ETOT);            // 3.4 MB
    float* h2     = h1;  // reuse: h1 dead after layer-1 aggregation

    const int eb = (ETOT + 255) / 256;

    // ---- CSR build (shared by both layers) ----
    hipMemsetAsync(deg, 0, (size_t)NNODES * 4, stream);
    deg_kernel<<<eb, 256, 0, stream>>>(ei, deg);
    scan_kernel<<<1, SCAN_T, 0, stream>>>(deg, rowptr);
    hipMemcpyAsync(cursor, rowptr, (size_t)(NNODES + 1) * 4, hipMemcpyDeviceToDevice, stream);
    scatter_kernel<<<eb, 256, 0, stream>>>(ei, cursor, srcs);

    // ---- Layer 1 ----
    dim3 g1((NNODES + BM - 1) / BM, C1 / BN);
    sgemm_kernel<<<g1, 256, 0, stream>>>(x, W1, h1, NNODES, C1, IN_DIM);
    alpha1_kernel<<<NNODES, 256, 0, stream>>>(h1, asrc1, adst1, as1, ad1);
    aggr1_csr<<<NNODES, 256, 0, stream>>>(rowptr, srcs, h1, as1, ad1, b1, act1);

    // ---- Layer 2 ----
    dim3 g2((NNODES + BM - 1) / BM, C2 / BN);
    sgemm_kernel<<<g2, 256, 0, stream>>>(act1, W2, h2, NNODES, C2, C1);
    alpha2_kernel<<<NNODES, 64, 0, stream>>>(h2, asrc2, adst2, as2, ad2);
    aggr2_csr<<<NNODES, 128, 0, stream>>>(rowptr, srcs, h2, as2, ad2, b2, out);
}

// Round 4
// 697.768 us; speedup vs baseline: 2.7927x; 1.4477x over previous
//
#include <hip/hip_runtime.h>
#include <math.h>

#define NNODES 50000
#define E0 800000
#define ETOT 850000
#define IN_DIM 1024
#define HEADS 4
#define C1 256      // HEADS*HID
#define C2 128      // OUT_DIM
#define NEG_SLOPE 0.2f

typedef short bf16x8 __attribute__((ext_vector_type(8)));
typedef float f32x4 __attribute__((ext_vector_type(4)));

// ---------- helpers ----------
// NOTE: harness delivers integer inputs as int32 (verified round 1: int* passed,
// long long* faulted). Do NOT read edge_index as int64.
__device__ __forceinline__ void edge_sd(const int* __restrict__ ei, int e, int& s, int& d) {
    if (e < E0) { s = ei[e]; d = ei[E0 + e]; }
    else        { s = e - E0; d = s; }
}

__device__ __forceinline__ unsigned short f2b(float f) {   // f32 -> bf16 RNE
    unsigned u = __float_as_uint(f);
    return (unsigned short)((u + 0x7fffu + ((u >> 16) & 1u)) >> 16);
}

__device__ __forceinline__ void gload_lds16(const void* g, void* l) {
    __builtin_amdgcn_global_load_lds(
        (const __attribute__((address_space(1))) unsigned int*)g,
        (__attribute__((address_space(3))) unsigned int*)l, 16, 0, 0);
}

// ---------- weight transpose + bf16 cast: W[K][N] f32 -> WT[N][K] bf16 ----------
__global__ __launch_bounds__(256) void wtrans_kernel(const float* __restrict__ W,
                                                     unsigned short* __restrict__ WT,
                                                     int K, int N)
{
    int idx = blockIdx.x * 256 + threadIdx.x;
    if (idx >= K * N) return;
    int k = idx / N, n = idx % N;
    WT[(size_t)n * K + k] = f2b(W[idx]);
}

// ---------- MFMA GEMM: C[M][N] f32 = A[M][K] f32 (cast bf16) @ BT[N][K] bf16 ----------
// 128x128 tile, BK=32, 4 waves (each 64x64 = 4x4 frags of 16x16x32).
// LDS layout [kchunk(4)][row(128)][8] bf16 so frag ds_read_b128 spreads banks.
__global__ __launch_bounds__(256) void gemm_bf16(const float* __restrict__ A,
                                                 const unsigned short* __restrict__ Bt,
                                                 float* __restrict__ C,
                                                 int M, int N, int K)
{
    __shared__ __align__(16) unsigned short As[4 * 128 * 8];
    __shared__ __align__(16) unsigned short Bs[4 * 128 * 8];

    const int tid  = threadIdx.x;
    const int lane = tid & 63;
    const int wid  = tid >> 6;
    const int wr   = wid >> 1, wc = wid & 1;
    const int rowBase = blockIdx.y * 128;
    const int colBase = blockIdx.x * 128;

    // A staging (reg path): thread t covers row=t>>1, k cols [(t&1)*16, +16)
    const int arow = tid >> 1;
    const int akh  = (tid & 1) * 2;               // first of two kchunks
    const int aGRow = min(rowBase + arow, M - 1); // clamp tail reads
    const float* aptr = A + (size_t)aGRow * K + akh * 8;
    unsigned short* awr0 = &As[akh * 1024 + arow * 8];
    unsigned short* awr1 = awr0 + 1024;

    // B staging via global_load_lds: wave w stages kchunk plane w, halves c=0/1
    const unsigned short* bptr = Bt + (size_t)(colBase + lane) * K + wid * 8;
    unsigned short* bwr0 = &Bs[wid * 1024];        // + lane*8 implicit
    unsigned short* bwr1 = bwr0 + 512;

    const int r0 = lane & 15;
    const int kh = lane >> 4;
    const unsigned short* ard = &As[kh * 1024 + (wr * 64 + r0) * 8];
    const unsigned short* brd = &Bs[kh * 1024 + (wc * 64 + r0) * 8];

    f32x4 zero = {0.f, 0.f, 0.f, 0.f};
    f32x4 acc[4][4];
    #pragma unroll
    for (int i = 0; i < 4; ++i)
        #pragma unroll
        for (int j = 0; j < 4; ++j) acc[i][j] = zero;

    for (int kt = 0; kt < K; kt += 32) {
        // A: 16 f32 -> 16 bf16 in regs (overlaps prev compute; before barrier)
        float4 f0 = *(const float4*)(aptr + kt + 0);
        float4 f1 = *(const float4*)(aptr + kt + 4);
        float4 f2 = *(const float4*)(aptr + kt + 8);
        float4 f3 = *(const float4*)(aptr + kt + 12);
        bf16x8 p0, p1;
        p0[0] = f2b(f0.x); p0[1] = f2b(f0.y); p0[2] = f2b(f0.z); p0[3] = f2b(f0.w);
        p0[4] = f2b(f1.x); p0[5] = f2b(f1.y); p0[6] = f2b(f1.z); p0[7] = f2b(f1.w);
        p1[0] = f2b(f2.x); p1[1] = f2b(f2.y); p1[2] = f2b(f2.z); p1[3] = f2b(f2.w);
        p1[4] = f2b(f3.x); p1[5] = f2b(f3.y); p1[6] = f2b(f3.z); p1[7] = f2b(f3.w);

        __syncthreads();                       // prev compute done, LDS free
        *(bf16x8*)awr0 = p0;
        *(bf16x8*)awr1 = p1;
        gload_lds16(bptr + kt, bwr0);
        gload_lds16(bptr + (size_t)64 * K + kt, bwr1);
        __syncthreads();                       // staging visible (full drain)

        bf16x8 af[4], bf[4];
        #pragma unroll
        for (int fi = 0; fi < 4; ++fi) af[fi] = *(const bf16x8*)(ard + fi * 128);
        #pragma unroll
        for (int fj = 0; fj < 4; ++fj) bf[fj] = *(const bf16x8*)(brd + fj * 128);
        #pragma unroll
        for (int fi = 0; fi < 4; ++fi)
            #pragma unroll
            for (int fj = 0; fj < 4; ++fj)
                acc[fi][fj] = __builtin_amdgcn_mfma_f32_16x16x32_bf16(
                    af[fi], bf[fj], acc[fi][fj], 0, 0, 0);
    }

    // C/D layout (m89-verified): col = lane&15, row = (lane>>4)*4 + reg
    #pragma unroll
    for (int fi = 0; fi < 4; ++fi) {
        int row0 = rowBase + wr * 64 + fi * 16 + kh * 4;
        #pragma unroll
        for (int i = 0; i < 4; ++i) {
            int row = row0 + i;
            if (row < M) {
                #pragma unroll
                for (int fj = 0; fj < 4; ++fj)
                    C[(size_t)row * N + colBase + wc * 64 + fj * 16 + r0] = acc[fi][fj][i];
            }
        }
    }
}

// ---------- per-node attention halves, layer 1 (H=4, D=64, 256 threads) ----------
__global__ __launch_bounds__(256) void alpha1_kernel(const float* __restrict__ h1,
                                                     const float* __restrict__ asrc,
                                                     const float* __restrict__ adst,
                                                     float* __restrict__ out_s,
                                                     float* __restrict__ out_d)
{
    int n = blockIdx.x;
    int t = threadIdx.x;
    float h = h1[(size_t)n * C1 + t];
    float s = h * asrc[t];
    float d = h * adst[t];
    #pragma unroll
    for (int off = 32; off > 0; off >>= 1) {
        s += __shfl_down(s, off);
        d += __shfl_down(d, off);
    }
    if ((t & 63) == 0) {
        out_s[n * HEADS + (t >> 6)] = s;
        out_d[n * HEADS + (t >> 6)] = d;
    }
}

// ---------- per-node attention halves, layer 2 (H=1, D=128, 64 threads) ----------
__global__ __launch_bounds__(64) void alpha2_kernel(const float* __restrict__ h2,
                                                    const float* __restrict__ asrc,
                                                    const float* __restrict__ adst,
                                                    float* __restrict__ out_s,
                                                    float* __restrict__ out_d)
{
    int n = blockIdx.x;
    int t = threadIdx.x;
    float a = h2[(size_t)n * C2 + t];
    float b = h2[(size_t)n * C2 + t + 64];
    float s = a * asrc[t] + b * asrc[t + 64];
    float d = a * adst[t] + b * adst[t + 64];
    #pragma unroll
    for (int off = 32; off > 0; off >>= 1) {
        s += __shfl_down(s, off);
        d += __shfl_down(d, off);
    }
    if (t == 0) { out_s[n] = s; out_d[n] = d; }
}

// ---------- CSR build ----------
__global__ __launch_bounds__(256) void deg_kernel(const int* __restrict__ ei,
                                                  int* __restrict__ deg)
{
    int e = blockIdx.x * blockDim.x + threadIdx.x;
    if (e >= ETOT) return;
    int s, d; edge_sd(ei, e, s, d);
    atomicAdd(&deg[d], 1);
}

#define SCAN_T 1024
__global__ __launch_bounds__(SCAN_T) void scan_kernel(const int* __restrict__ deg,
                                                      int* __restrict__ rowptr)
{
    __shared__ int buf[SCAN_T];
    __shared__ int carry_s;
    int t = threadIdx.x;
    if (t == 0) carry_s = 0;
    __syncthreads();
    for (int base = 0; base < NNODES; base += SCAN_T) {
        int idx = base + t;
        int v = (idx < NNODES) ? deg[idx] : 0;
        buf[t] = v;
        __syncthreads();
        #pragma unroll
        for (int off = 1; off < SCAN_T; off <<= 1) {
            int add = (t >= off) ? buf[t - off] : 0;
            __syncthreads();
            buf[t] += add;
            __syncthreads();
        }
        int incl = buf[t];
        int carry = carry_s;
        if (idx < NNODES) rowptr[idx] = carry + incl - v;
        __syncthreads();
        if (t == SCAN_T - 1) carry_s = carry + incl;
        __syncthreads();
    }
    if (t == 0) rowptr[NNODES] = carry_s;
}

__global__ __launch_bounds__(256) void scatter_kernel(const int* __restrict__ ei,
                                                      int* __restrict__ cursor,
                                                      int* __restrict__ srcs)
{
    int e = blockIdx.x * blockDim.x + threadIdx.x;
    if (e >= ETOT) return;
    int s, d; edge_sd(ei, e, s, d);
    int pos = atomicAdd(&cursor[d], 1);
    srcs[pos] = s;
}

// ---------- layer-1 fused softmax-aggregate (+bias+ELU), one block per dst ----------
__global__ __launch_bounds__(256) void aggr1_csr(const int* __restrict__ rowptr,
                                                 const int* __restrict__ srcs,
                                                 const float* __restrict__ h1,
                                                 const float* __restrict__ as1,
                                                 const float* __restrict__ ad1,
                                                 const float* __restrict__ b1,
                                                 float* __restrict__ out)
{
    int d = blockIdx.x;
    int t = threadIdx.x;
    int head = t >> 6;
    int beg = rowptr[d], end = rowptr[d + 1];
    float add = ad1[d * HEADS + head];
    float m = -INFINITY, ssum = 0.f, acc = 0.f;
    for (int i = beg; i < end; ++i) {
        int s = srcs[i];
        float e = as1[s * HEADS + head] + add;
        e = e > 0.f ? e : NEG_SLOPE * e;
        float h = h1[(size_t)s * C1 + t];
        if (e > m) {
            float r = expf(m - e);   // exp(-inf)=0 first time
            ssum *= r; acc *= r; m = e;
        }
        float w = expf(e - m);
        ssum += w;
        acc += w * h;
    }
    float o = acc / (ssum + 1e-16f) + b1[t];
    out[(size_t)d * C1 + t] = o > 0.f ? o : (expf(o) - 1.f);
}

// ---------- layer-2 fused softmax-aggregate (+bias+L2 normalize) ----------
__global__ __launch_bounds__(128) void aggr2_csr(const int* __restrict__ rowptr,
                                                 const int* __restrict__ srcs,
                                                 const float* __restrict__ h2,
                                                 const float* __restrict__ as2,
                                                 const float* __restrict__ ad2,
                                                 const float* __restrict__ b2,
                                                 float* __restrict__ out)
{
    int d = blockIdx.x;
    int t = threadIdx.x;
    int beg = rowptr[d], end = rowptr[d + 1];
    float add = ad2[d];
    float m = -INFINITY, ssum = 0.f, acc = 0.f;
    for (int i = beg; i < end; ++i) {
        int s = srcs[i];
        float e = as2[s] + add;
        e = e > 0.f ? e : NEG_SLOPE * e;
        float h = h2[(size_t)s * C2 + t];
        if (e > m) {
            float r = expf(m - e);
            ssum *= r; acc *= r; m = e;
        }
        float w = expf(e - m);
        ssum += w;
        acc += w * h;
    }
    float o = acc / (ssum + 1e-16f) + b2[t];
    __shared__ float red[2];
    float sq = o * o;
    #pragma unroll
    for (int off = 32; off > 0; off >>= 1) sq += __shfl_down(sq, off);
    if ((t & 63) == 0) red[t >> 6] = sq;
    __syncthreads();
    float total = red[0] + red[1];
    float inv = 1.0f / fmaxf(sqrtf(total), 1e-12f);
    out[(size_t)d * C2 + t] = o * inv;
}

extern "C" void kernel_launch(void* const* d_in, const int* in_sizes, int n_in,
                              void* d_out, int out_size, void* d_ws, size_t ws_size,
                              hipStream_t stream)
{
    const float* x     = (const float*)d_in[0];
    const int*   ei    = (const int*)d_in[1];
    const float* W1    = (const float*)d_in[2];
    const float* asrc1 = (const float*)d_in[3];
    const float* adst1 = (const float*)d_in[4];
    const float* b1    = (const float*)d_in[5];
    const float* W2    = (const float*)d_in[6];
    const float* asrc2 = (const float*)d_in[7];
    const float* adst2 = (const float*)d_in[8];
    const float* b2    = (const float*)d_in[9];
    float* out = (float*)d_out;

    char* ws = (char*)d_ws;
    size_t off = 0;
    auto alloc = [&](size_t nfloats) {
        float* p = (float*)(ws + off);
        off += nfloats * sizeof(float);
        return p;
    };
    float*          h1     = alloc((size_t)NNODES * C1);   // 51.2 MB
    float*          act1   = alloc((size_t)NNODES * C1);   // 51.2 MB
    unsigned short* W1T    = (unsigned short*)alloc((size_t)C1 * IN_DIM / 2);  // bf16 [256][1024]
    unsigned short* W2T    = (unsigned short*)alloc((size_t)C2 * C1 / 2);      // bf16 [128][256]
    float*          as1    = alloc((size_t)NNODES * HEADS);
    float*          ad1    = alloc((size_t)NNODES * HEADS);
    float*          as2    = alloc(NNODES);
    float*          ad2    = alloc(NNODES);
    int*            deg    = (int*)alloc(NNODES);
    int*            rowptr = (int*)alloc(NNODES + 1);
    int*            cursor = (int*)alloc(NNODES + 1);
    int*            srcs   = (int*)alloc(ETOT);            // 3.4 MB
    float*          h2     = h1;  // reuse: h1 dead after layer-1 aggregation

    const int eb = (ETOT + 255) / 256;

    // ---- weight prep ----
    wtrans_kernel<<<(IN_DIM * C1 + 255) / 256, 256, 0, stream>>>(W1, W1T, IN_DIM, C1);
    wtrans_kernel<<<(C1 * C2 + 255) / 256, 256, 0, stream>>>(W2, W2T, C1, C2);

    // ---- CSR build (shared by both layers) ----
    hipMemsetAsync(deg, 0, (size_t)NNODES * 4, stream);
    deg_kernel<<<eb, 256, 0, stream>>>(ei, deg);
    scan_kernel<<<1, SCAN_T, 0, stream>>>(deg, rowptr);
    hipMemcpyAsync(cursor, rowptr, (size_t)(NNODES + 1) * 4, hipMemcpyDeviceToDevice, stream);
    scatter_kernel<<<eb, 256, 0, stream>>>(ei, cursor, srcs);

    // ---- Layer 1 ----
    dim3 g1(C1 / 128, (NNODES + 127) / 128);   // col-fastest: A panels reuse L2
    gemm_bf16<<<g1, 256, 0, stream>>>(x, W1T, h1, NNODES, C1, IN_DIM);
    alpha1_kernel<<<NNODES, 256, 0, stream>>>(h1, asrc1, adst1, as1, ad1);
    aggr1_csr<<<NNODES, 256, 0, stream>>>(rowptr, srcs, h1, as1, ad1, b1, act1);

    // ---- Layer 2 ----
    dim3 g2(C2 / 128, (NNODES + 127) / 128);
    gemm_bf16<<<g2, 256, 0, stream>>>(act1, W2T, h2, NNODES, C2, C1);
    alpha2_kernel<<<NNODES, 64, 0, stream>>>(h2, asrc2, adst2, as2, ad2);
    aggr2_csr<<<NNODES, 128, 0, stream>>>(rowptr, srcs, h2, as2, ad2, b2, out);
}

// Round 6
// 535.426 us; speedup vs baseline: 3.6394x; 1.3032x over previous
//
#include <hip/hip_runtime.h>
#include <math.h>

#define NNODES 50000
#define E0 800000
#define ETOT 850000
#define IN_DIM 1024
#define HEADS 4
#define C1 256      // HEADS*HID
#define C2 128      // OUT_DIM
#define NEG_SLOPE 0.2f

typedef short bf16x8 __attribute__((ext_vector_type(8)));
typedef float f32x4 __attribute__((ext_vector_type(4)));
typedef unsigned short ushort_t;

// ---------- helpers ----------
// NOTE: harness delivers integer inputs as int32 (verified round 1: int* passed,
// long long* faulted). Do NOT read edge_index as int64.
__device__ __forceinline__ void edge_sd(const int* __restrict__ ei, int e, int& s, int& d) {
    if (e < E0) { s = ei[e]; d = ei[E0 + e]; }
    else        { s = e - E0; d = s; }
}

__device__ __forceinline__ ushort_t f2b(float f) {   // f32 -> bf16 RNE
    unsigned u = __float_as_uint(f);
    return (ushort_t)((u + 0x7fffu + ((u >> 16) & 1u)) >> 16);
}
__device__ __forceinline__ float bf2f(ushort_t u) {
    return __uint_as_float((unsigned)u << 16);
}
__device__ __forceinline__ float lrelu(float v) { return v > 0.f ? v : NEG_SLOPE * v; }

__device__ __forceinline__ void gload_lds16(const void* g, void* l) {
    __builtin_amdgcn_global_load_lds(
        (const __attribute__((address_space(1))) unsigned int*)g,
        (__attribute__((address_space(3))) unsigned int*)l, 16, 0, 0);
}

// ---------- weight transpose + bf16 cast: W[K][N] f32 -> WT[N][K] bf16 ----------
__global__ __launch_bounds__(256) void wtrans_kernel(const float* __restrict__ W,
                                                     ushort_t* __restrict__ WT,
                                                     int K, int N)
{
    int idx = blockIdx.x * 256 + threadIdx.x;
    if (idx >= K * N) return;
    int k = idx / N, n = idx % N;
    WT[(size_t)n * K + k] = f2b(W[idx]);
}

// ---------- MFMA GEMM (A f32, cast in regs): Cb bf16 = A[M][K] @ Bt[N][K] ----------
// 128x128 tile, BK=32, 4 waves. LDS [kchunk(4)][row(128)][8] bf16.
__global__ __launch_bounds__(256) void gemm_fb(const float* __restrict__ A,
                                               const ushort_t* __restrict__ Bt,
                                               ushort_t* __restrict__ Cb,
                                               int M, int N, int K)
{
    __shared__ __align__(16) ushort_t As[4 * 128 * 8];
    __shared__ __align__(16) ushort_t Bs[4 * 128 * 8];

    const int tid  = threadIdx.x;
    const int lane = tid & 63;
    const int wid  = tid >> 6;
    const int wr   = wid >> 1, wc = wid & 1;
    const int rowBase = blockIdx.y * 128;
    const int colBase = blockIdx.x * 128;

    const int arow = tid >> 1;
    const int akh  = (tid & 1) * 2;
    const int aGRow = min(rowBase + arow, M - 1);
    const float* aptr = A + (size_t)aGRow * K + akh * 8;
    ushort_t* awr0 = &As[akh * 1024 + arow * 8];
    ushort_t* awr1 = awr0 + 1024;

    const ushort_t* bptr = Bt + (size_t)(colBase + lane) * K + wid * 8;
    ushort_t* bwr0 = &Bs[wid * 1024];
    ushort_t* bwr1 = bwr0 + 512;

    const int r0 = lane & 15;
    const int kh = lane >> 4;
    const ushort_t* ard = &As[kh * 1024 + (wr * 64 + r0) * 8];
    const ushort_t* brd = &Bs[kh * 1024 + (wc * 64 + r0) * 8];

    f32x4 zero = {0.f, 0.f, 0.f, 0.f};
    f32x4 acc[4][4];
    #pragma unroll
    for (int i = 0; i < 4; ++i)
        #pragma unroll
        for (int j = 0; j < 4; ++j) acc[i][j] = zero;

    for (int kt = 0; kt < K; kt += 32) {
        float4 f0 = *(const float4*)(aptr + kt + 0);
        float4 f1 = *(const float4*)(aptr + kt + 4);
        float4 f2 = *(const float4*)(aptr + kt + 8);
        float4 f3 = *(const float4*)(aptr + kt + 12);
        bf16x8 p0, p1;
        p0[0] = f2b(f0.x); p0[1] = f2b(f0.y); p0[2] = f2b(f0.z); p0[3] = f2b(f0.w);
        p0[4] = f2b(f1.x); p0[5] = f2b(f1.y); p0[6] = f2b(f1.z); p0[7] = f2b(f1.w);
        p1[0] = f2b(f2.x); p1[1] = f2b(f2.y); p1[2] = f2b(f2.z); p1[3] = f2b(f2.w);
        p1[4] = f2b(f3.x); p1[5] = f2b(f3.y); p1[6] = f2b(f3.z); p1[7] = f2b(f3.w);

        __syncthreads();
        *(bf16x8*)awr0 = p0;
        *(bf16x8*)awr1 = p1;
        gload_lds16(bptr + kt, bwr0);
        gload_lds16(bptr + (size_t)64 * K + kt, bwr1);
        __syncthreads();

        bf16x8 af[4], bfr[4];
        #pragma unroll
        for (int fi = 0; fi < 4; ++fi) af[fi] = *(const bf16x8*)(ard + fi * 128);
        #pragma unroll
        for (int fj = 0; fj < 4; ++fj) bfr[fj] = *(const bf16x8*)(brd + fj * 128);
        #pragma unroll
        for (int fi = 0; fi < 4; ++fi)
            #pragma unroll
            for (int fj = 0; fj < 4; ++fj)
                acc[fi][fj] = __builtin_amdgcn_mfma_f32_16x16x32_bf16(
                    af[fi], bfr[fj], acc[fi][fj], 0, 0, 0);
    }

    // C/D layout (m89-verified): col = lane&15, row = (lane>>4)*4 + reg
    #pragma unroll
    for (int fi = 0; fi < 4; ++fi) {
        int row0 = rowBase + wr * 64 + fi * 16 + kh * 4;
        #pragma unroll
        for (int i = 0; i < 4; ++i) {
            int row = row0 + i;
            if (row < M) {
                #pragma unroll
                for (int fj = 0; fj < 4; ++fj)
                    Cb[(size_t)row * N + colBase + wc * 64 + fj * 16 + r0] = f2b(acc[fi][fj][i]);
            }
        }
    }
}

// ---------- MFMA GEMM (A bf16 direct, gload_lds staging both sides) ----------
__global__ __launch_bounds__(256) void gemm_bb(const ushort_t* __restrict__ Ab,
                                               const ushort_t* __restrict__ Bt,
                                               ushort_t* __restrict__ Cb,
                                               int M, int N, int K)
{
    __shared__ __align__(16) ushort_t As[4 * 128 * 8];
    __shared__ __align__(16) ushort_t Bs[4 * 128 * 8];

    const int tid  = threadIdx.x;
    const int lane = tid & 63;
    const int wid  = tid >> 6;
    const int wr   = wid >> 1, wc = wid & 1;
    const int rowBase = blockIdx.y * 128;
    const int colBase = blockIdx.x * 128;

    const ushort_t* aptr0 = Ab + (size_t)min(rowBase + lane, M - 1) * K + wid * 8;
    const ushort_t* aptr1 = Ab + (size_t)min(rowBase + 64 + lane, M - 1) * K + wid * 8;
    ushort_t* awr0 = &As[wid * 1024];
    ushort_t* awr1 = awr0 + 512;

    const ushort_t* bptr = Bt + (size_t)(colBase + lane) * K + wid * 8;
    ushort_t* bwr0 = &Bs[wid * 1024];
    ushort_t* bwr1 = bwr0 + 512;

    const int r0 = lane & 15;
    const int kh = lane >> 4;
    const ushort_t* ard = &As[kh * 1024 + (wr * 64 + r0) * 8];
    const ushort_t* brd = &Bs[kh * 1024 + (wc * 64 + r0) * 8];

    f32x4 zero = {0.f, 0.f, 0.f, 0.f};
    f32x4 acc[4][4];
    #pragma unroll
    for (int i = 0; i < 4; ++i)
        #pragma unroll
        for (int j = 0; j < 4; ++j) acc[i][j] = zero;

    for (int kt = 0; kt < K; kt += 32) {
        __syncthreads();                 // prev iter's reads done
        gload_lds16(aptr0 + kt, awr0);
        gload_lds16(aptr1 + kt, awr1);
        gload_lds16(bptr + kt, bwr0);
        gload_lds16(bptr + (size_t)64 * K + kt, bwr1);
        __syncthreads();                 // staging drained

        bf16x8 af[4], bfr[4];
        #pragma unroll
        for (int fi = 0; fi < 4; ++fi) af[fi] = *(const bf16x8*)(ard + fi * 128);
        #pragma unroll
        for (int fj = 0; fj < 4; ++fj) bfr[fj] = *(const bf16x8*)(brd + fj * 128);
        #pragma unroll
        for (int fi = 0; fi < 4; ++fi)
            #pragma unroll
            for (int fj = 0; fj < 4; ++fj)
                acc[fi][fj] = __builtin_amdgcn_mfma_f32_16x16x32_bf16(
                    af[fi], bfr[fj], acc[fi][fj], 0, 0, 0);
    }

    #pragma unroll
    for (int fi = 0; fi < 4; ++fi) {
        int row0 = rowBase + wr * 64 + fi * 16 + kh * 4;
        #pragma unroll
        for (int i = 0; i < 4; ++i) {
            int row = row0 + i;
            if (row < M) {
                #pragma unroll
                for (int fj = 0; fj < 4; ++fj)
                    Cb[(size_t)row * N + colBase + wc * 64 + fj * 16 + r0] = f2b(acc[fi][fj][i]);
            }
        }
    }
}

// ---------- per-node attention halves, layer 1 (bf16 h1) ----------
__global__ __launch_bounds__(256) void alpha1_kernel(const ushort_t* __restrict__ h1b,
                                                     const float* __restrict__ asrc,
                                                     const float* __restrict__ adst,
                                                     float* __restrict__ out_s,
                                                     float* __restrict__ out_d)
{
    int n = blockIdx.x;
    int t = threadIdx.x;
    float h = bf2f(h1b[(size_t)n * C1 + t]);
    float s = h * asrc[t];
    float d = h * adst[t];
    #pragma unroll
    for (int off = 32; off > 0; off >>= 1) {
        s += __shfl_down(s, off);
        d += __shfl_down(d, off);
    }
    if ((t & 63) == 0) {
        out_s[n * HEADS + (t >> 6)] = s;
        out_d[n * HEADS + (t >> 6)] = d;
    }
}

// ---------- per-node attention halves, layer 2 (bf16 h2) ----------
__global__ __launch_bounds__(64) void alpha2_kernel(const ushort_t* __restrict__ h2b,
                                                    const float* __restrict__ asrc,
                                                    const float* __restrict__ adst,
                                                    float* __restrict__ out_s,
                                                    float* __restrict__ out_d)
{
    int n = blockIdx.x;
    int t = threadIdx.x;
    float a = bf2f(h2b[(size_t)n * C2 + t]);
    float b = bf2f(h2b[(size_t)n * C2 + t + 64]);
    float s = a * asrc[t] + b * asrc[t + 64];
    float d = a * adst[t] + b * adst[t + 64];
    #pragma unroll
    for (int off = 32; off > 0; off >>= 1) {
        s += __shfl_down(s, off);
        d += __shfl_down(d, off);
    }
    if (t == 0) { out_s[n] = s; out_d[n] = d; }
}

// ---------- CSR build ----------
__global__ __launch_bounds__(256) void deg_kernel(const int* __restrict__ ei,
                                                  int* __restrict__ deg)
{
    int e = blockIdx.x * blockDim.x + threadIdx.x;
    if (e >= ETOT) return;
    int s, d; edge_sd(ei, e, s, d);
    atomicAdd(&deg[d], 1);
}

// 4 elems/thread + wave shfl scan: 4 barriers/chunk instead of 20 (was 980 total).
#define SCAN_T 1024
__global__ __launch_bounds__(SCAN_T) void scan_kernel(const int* __restrict__ deg,
                                                      int* __restrict__ rowptr)
{
    __shared__ int wsum[16];
    __shared__ int chunk_tot;
    __shared__ int carry_s;
    const int t = threadIdx.x, lane = t & 63, w = t >> 6;
    if (t == 0) carry_s = 0;
    __syncthreads();
    for (int base = 0; base < NNODES; base += SCAN_T * 4) {
        int idx = base + t * 4;
        int v0 = (idx + 0 < NNODES) ? deg[idx + 0] : 0;
        int v1 = (idx + 1 < NNODES) ? deg[idx + 1] : 0;
        int v2 = (idx + 2 < NNODES) ? deg[idx + 2] : 0;
        int v3 = (idx + 3 < NNODES) ? deg[idx + 3] : 0;
        int p0 = v0, p1 = p0 + v1, p2 = p1 + v2, p3 = p2 + v3;
        int incl = p3;
        #pragma unroll
        for (int off = 1; off < 64; off <<= 1) {
            int nb = __shfl_up(incl, off);
            if (lane >= off) incl += nb;
        }
        if (lane == 63) wsum[w] = incl;
        __syncthreads();
        if (w == 0 && lane < 16) {
            int ws = wsum[lane];
            int wincl = ws;
            #pragma unroll
            for (int off = 1; off < 16; off <<= 1) {
                int nb = __shfl_up(wincl, off);
                if (lane >= off) wincl += nb;
            }
            wsum[lane] = wincl - ws;            // exclusive
            if (lane == 15) chunk_tot = wincl;
        }
        __syncthreads();
        int carry = carry_s;
        int basev = carry + wsum[w] + (incl - p3);
        if (idx + 0 < NNODES) rowptr[idx + 0] = basev;
        if (idx + 1 < NNODES) rowptr[idx + 1] = basev + p0;
        if (idx + 2 < NNODES) rowptr[idx + 2] = basev + p1;
        if (idx + 3 < NNODES) rowptr[idx + 3] = basev + p2;
        __syncthreads();
        if (t == 0) carry_s = carry + chunk_tot;
        __syncthreads();
    }
    if (threadIdx.x == 0) rowptr[NNODES] = carry_s;
}

__global__ __launch_bounds__(256) void scatter_kernel(const int* __restrict__ ei,
                                                      int* __restrict__ cursor,
                                                      int* __restrict__ srcs)
{
    int e = blockIdx.x * blockDim.x + threadIdx.x;
    if (e >= ETOT) return;
    int s, d; edge_sd(ei, e, s, d);
    int pos = atomicAdd(&cursor[d], 1);
    srcs[pos] = s;
}

// ---------- per-edge normalized attention weights, layer 1 (4 heads) ----------
// One wave per dst; two-pass (max, then exp/sum) = exact reference semantics.
__global__ __launch_bounds__(256) void weights1_kernel(const int* __restrict__ rowptr,
                                                       const int* __restrict__ srcs,
                                                       const float4* __restrict__ as1,
                                                       const float4* __restrict__ ad1,
                                                       float4* __restrict__ wbuf)
{
    int d = blockIdx.x * 4 + (threadIdx.x >> 6);
    if (d >= NNODES) return;
    int lane = threadIdx.x & 63;
    int beg = rowptr[d], end = rowptr[d + 1];
    float4 adv = ad1[d];
    float m0 = -INFINITY, m1 = -INFINITY, m2 = -INFINITY, m3 = -INFINITY;
    for (int i = beg + lane; i < end; i += 64) {
        int s = srcs[i];
        float4 av = as1[s];
        m0 = fmaxf(m0, lrelu(av.x + adv.x));
        m1 = fmaxf(m1, lrelu(av.y + adv.y));
        m2 = fmaxf(m2, lrelu(av.z + adv.z));
        m3 = fmaxf(m3, lrelu(av.w + adv.w));
    }
    #pragma unroll
    for (int off = 32; off > 0; off >>= 1) {
        m0 = fmaxf(m0, __shfl_xor(m0, off));
        m1 = fmaxf(m1, __shfl_xor(m1, off));
        m2 = fmaxf(m2, __shfl_xor(m2, off));
        m3 = fmaxf(m3, __shfl_xor(m3, off));
    }
    float s0 = 0.f, s1 = 0.f, s2 = 0.f, s3 = 0.f;
    for (int i = beg + lane; i < end; i += 64) {
        int s = srcs[i];
        float4 av = as1[s];
        float w0 = expf(lrelu(av.x + adv.x) - m0);
        float w1 = expf(lrelu(av.y + adv.y) - m1);
        float w2 = expf(lrelu(av.z + adv.z) - m2);
        float w3 = expf(lrelu(av.w + adv.w) - m3);
        wbuf[i] = make_float4(w0, w1, w2, w3);
        s0 += w0; s1 += w1; s2 += w2; s3 += w3;
    }
    #pragma unroll
    for (int off = 32; off > 0; off >>= 1) {
        s0 += __shfl_xor(s0, off);
        s1 += __shfl_xor(s1, off);
        s2 += __shfl_xor(s2, off);
        s3 += __shfl_xor(s3, off);
    }
    float i0 = 1.f / (s0 + 1e-16f), i1 = 1.f / (s1 + 1e-16f);
    float i2 = 1.f / (s2 + 1e-16f), i3 = 1.f / (s3 + 1e-16f);
    for (int i = beg + lane; i < end; i += 64) {
        float4 wv = wbuf[i];
        wbuf[i] = make_float4(wv.x * i0, wv.y * i1, wv.z * i2, wv.w * i3);
    }
}

// ---------- per-edge normalized attention weights, layer 2 (1 head) ----------
__global__ __launch_bounds__(256) void weights2_kernel(const int* __restrict__ rowptr,
                                                       const int* __restrict__ srcs,
                                                       const float* __restrict__ as2,
                                                       const float* __restrict__ ad2,
                                                       float* __restrict__ wbuf)
{
    int d = blockIdx.x * 4 + (threadIdx.x >> 6);
    if (d >= NNODES) return;
    int lane = threadIdx.x & 63;
    int beg = rowptr[d], end = rowptr[d + 1];
    float adv = ad2[d];
    float m = -INFINITY;
    for (int i = beg + lane; i < end; i += 64)
        m = fmaxf(m, lrelu(as2[srcs[i]] + adv));
    #pragma unroll
    for (int off = 32; off > 0; off >>= 1) m = fmaxf(m, __shfl_xor(m, off));
    float sm = 0.f;
    for (int i = beg + lane; i < end; i += 64) {
        float w = expf(lrelu(as2[srcs[i]] + adv) - m);
        wbuf[i] = w;
        sm += w;
    }
    #pragma unroll
    for (int off = 32; off > 0; off >>= 1) sm += __shfl_xor(sm, off);
    float inv = 1.f / (sm + 1e-16f);
    for (int i = beg + lane; i < end; i += 64) wbuf[i] *= inv;
}

// ---------- layer-1 aggregation: pure weighted gather (+bias+ELU), bf16 in/out ----------
__global__ __launch_bounds__(256) void aggr1_csr(const int* __restrict__ rowptr,
                                                 const int* __restrict__ srcs,
                                                 const ushort_t* __restrict__ h1b,
                                                 const float* __restrict__ wbuf,
                                                 const float* __restrict__ b1,
                                                 ushort_t* __restrict__ out)
{
    int d = blockIdx.x;
    int t = threadIdx.x;
    int head = t >> 6;
    int beg = rowptr[d], end = rowptr[d + 1];
    float acc = 0.f;
    int i = beg;
    for (; i + 1 < end; i += 2) {
        int s0 = srcs[i], s1 = srcs[i + 1];
        float a0 = wbuf[i * 4 + head], a1 = wbuf[i * 4 + 4 + head];
        float v0 = bf2f(h1b[(size_t)s0 * C1 + t]);
        float v1 = bf2f(h1b[(size_t)s1 * C1 + t]);
        acc = fmaf(a0, v0, acc);
        acc = fmaf(a1, v1, acc);
    }
    if (i < end) {
        int s0 = srcs[i];
        acc = fmaf(wbuf[i * 4 + head], bf2f(h1b[(size_t)s0 * C1 + t]), acc);
    }
    float o = acc + b1[t];
    out[(size_t)d * C1 + t] = f2b(o > 0.f ? o : (expf(o) - 1.f));
}

// ---------- layer-2 aggregation (+bias+L2 normalize), bf16 in, f32 out ----------
__global__ __launch_bounds__(128) void aggr2_csr(const int* __restrict__ rowptr,
                                                 const int* __restrict__ srcs,
                                                 const ushort_t* __restrict__ h2b,
                                                 const float* __restrict__ wbuf,
                                                 const float* __restrict__ b2,
                                                 float* __restrict__ out)
{
    int d = blockIdx.x;
    int t = threadIdx.x;
    int beg = rowptr[d], end = rowptr[d + 1];
    float acc = 0.f;
    int i = beg;
    for (; i + 1 < end; i += 2) {
        int s0 = srcs[i], s1 = srcs[i + 1];
        float a0 = wbuf[i], a1 = wbuf[i + 1];
        float v0 = bf2f(h2b[(size_t)s0 * C2 + t]);
        float v1 = bf2f(h2b[(size_t)s1 * C2 + t]);
        acc = fmaf(a0, v0, acc);
        acc = fmaf(a1, v1, acc);
    }
    if (i < end) acc = fmaf(wbuf[i], bf2f(h2b[(size_t)srcs[i] * C2 + t]), acc);
    float o = acc + b2[t];
    __shared__ float red[2];
    float sq = o * o;
    #pragma unroll
    for (int off = 32; off > 0; off >>= 1) sq += __shfl_down(sq, off);
    if ((t & 63) == 0) red[t >> 6] = sq;
    __syncthreads();
    float total = red[0] + red[1];
    float inv = 1.0f / fmaxf(sqrtf(total), 1e-12f);
    out[(size_t)d * C2 + t] = o * inv;
}

extern "C" void kernel_launch(void* const* d_in, const int* in_sizes, int n_in,
                              void* d_out, int out_size, void* d_ws, size_t ws_size,
                              hipStream_t stream)
{
    const float* x     = (const float*)d_in[0];
    const int*   ei    = (const int*)d_in[1];
    const float* W1    = (const float*)d_in[2];
    const float* asrc1 = (const float*)d_in[3];
    const float* adst1 = (const float*)d_in[4];
    const float* b1    = (const float*)d_in[5];
    const float* W2    = (const float*)d_in[6];
    const float* asrc2 = (const float*)d_in[7];
    const float* adst2 = (const float*)d_in[8];
    const float* b2    = (const float*)d_in[9];
    float* out = (float*)d_out;

    char* ws = (char*)d_ws;
    size_t off = 0;
    auto alloc = [&](size_t nbytes) {
        void* p = ws + off;
        off += (nbytes + 15) & ~(size_t)15;
        return p;
    };
    ushort_t* h1b    = (ushort_t*)alloc((size_t)NNODES * C1 * 2);   // 25.6 MB
    ushort_t* act1b  = (ushort_t*)alloc((size_t)NNODES * C1 * 2);   // 25.6 MB
    ushort_t* h2b    = (ushort_t*)alloc((size_t)NNODES * C2 * 2);   // 12.8 MB
    ushort_t* W1T    = (ushort_t*)alloc((size_t)C1 * IN_DIM * 2);
    ushort_t* W2T    = (ushort_t*)alloc((size_t)C2 * C1 * 2);
    float*    as1    = (float*)alloc((size_t)NNODES * HEADS * 4);
    float*    ad1    = (float*)alloc((size_t)NNODES * HEADS * 4);
    float*    as2    = (float*)alloc((size_t)NNODES * 4);
    float*    ad2    = (float*)alloc((size_t)NNODES * 4);
    float*    wbuf1  = (float*)alloc((size_t)ETOT * HEADS * 4);     // 13.6 MB
    float*    wbuf2  = (float*)alloc((size_t)ETOT * 4);             // 3.4 MB
    int*      deg    = (int*)alloc((size_t)NNODES * 4);
    int*      rowptr = (int*)alloc((size_t)(NNODES + 1) * 4);
    int*      cursor = (int*)alloc((size_t)(NNODES + 1) * 4);
    int*      srcs   = (int*)alloc((size_t)ETOT * 4);               // 3.4 MB

    const int eb = (ETOT + 255) / 256;
    const int nb4 = (NNODES + 3) / 4;

    // ---- weight prep ----
    wtrans_kernel<<<(IN_DIM * C1 + 255) / 256, 256, 0, stream>>>(W1, W1T, IN_DIM, C1);
    wtrans_kernel<<<(C1 * C2 + 255) / 256, 256, 0, stream>>>(W2, W2T, C1, C2);

    // ---- CSR build ----
    hipMemsetAsync(deg, 0, (size_t)NNODES * 4, stream);
    deg_kernel<<<eb, 256, 0, stream>>>(ei, deg);
    scan_kernel<<<1, SCAN_T, 0, stream>>>(deg, rowptr);
    hipMemcpyAsync(cursor, rowptr, (size_t)(NNODES + 1) * 4, hipMemcpyDeviceToDevice, stream);
    scatter_kernel<<<eb, 256, 0, stream>>>(ei, cursor, srcs);

    // ---- Layer 1 ----
    dim3 g1(C1 / 128, (NNODES + 127) / 128);
    gemm_fb<<<g1, 256, 0, stream>>>(x, W1T, h1b, NNODES, C1, IN_DIM);
    alpha1_kernel<<<NNODES, 256, 0, stream>>>(h1b, asrc1, adst1, as1, ad1);
    weights1_kernel<<<nb4, 256, 0, stream>>>(rowptr, srcs, (const float4*)as1,
                                             (const float4*)ad1, (float4*)wbuf1);
    aggr1_csr<<<NNODES, 256, 0, stream>>>(rowptr, srcs, h1b, wbuf1, b1, act1b);

    // ---- Layer 2 ----
    dim3 g2(C2 / 128, (NNODES + 127) / 128);
    gemm_bb<<<g2, 256, 0, stream>>>(act1b, W2T, h2b, NNODES, C2, C1);
    alpha2_kernel<<<NNODES, 64, 0, stream>>>(h2b, asrc2, adst2, as2, ad2);
    weights2_kernel<<<nb4, 256, 0, stream>>>(rowptr, srcs, as2, ad2, wbuf2);
    aggr2_csr<<<NNODES, 128, 0, stream>>>(rowptr, srcs, h2b, wbuf2, b2, out);
}